// Round 11
// baseline (104.245 us; speedup 1.0000x reference)
//
#include <hip/hip_runtime.h>
#include <stdint.h>

#define UNITS 1024
#define BATCH 4096
#define FOURU 4096

typedef __bf16 bf16x8 __attribute__((ext_vector_type(8)));
typedef float f32x4 __attribute__((ext_vector_type(4)));

// round-to-nearest-even f32 -> bf16
__device__ __forceinline__ uint16_t f2bf(float f) {
  uint32_t u = __builtin_bit_cast(uint32_t, f);
  u += 0x7FFFu + ((u >> 16) & 1u);
  return (uint16_t)(u >> 16);
}
__device__ __forceinline__ float bf2f(uint16_t b) {
  uint32_t u = ((uint32_t)b) << 16;
  return __builtin_bit_cast(float, u);
}
__device__ __forceinline__ float fsig(float x) {
  return 1.0f / (1.0f + __expf(-x));
}
__device__ __forceinline__ f32x4 mfma16x16x32(bf16x8 a, bf16x8 b, f32x4 c) {
  return __builtin_amdgcn_mfma_f32_16x16x32_bf16(a, b, c, 0, 0, 0);
}

// async global->LDS, 16B per lane; LDS dest wave-uniform base (+lane*16 HW)
__device__ __forceinline__ void gll16(uint16_t* lds, const uint16_t* g) {
  __builtin_amdgcn_global_load_lds(
      (const __attribute__((address_space(1))) uint32_t*)g,
      (__attribute__((address_space(3))) uint32_t*)lds, 16, 0, 0);
}

// Granule swizzle (BK=32 tile = [ROWS][4 granules of 8 bf16]); stored granule
// (row,s) holds global (row, kg = s ^ ((row>>1)&3)). gload_lds dest LINEAR;
// permutation in per-lane GLOBAL source. Verified: conflicts 2.1M -> 0.
__device__ __forceinline__ int fidx(int row, int l4) {
  return row * 4 + (l4 ^ ((row >> 1) & 3));
}

template <int ROWS>
__device__ __forceinline__ void stage32s(const uint16_t* __restrict__ src,
                                         uint16_t* lds, int tid) {
  const int wb = tid & 192;  // wave*64 granules (linear LDS dest)
#pragma unroll
  for (int p = 0; p < ROWS / 64; ++p) {
    const int gi = p * 256 + tid;
    const int row = gi >> 2;
    const int kg = (gi & 3) ^ ((row >> 1) & 3);
    gll16(lds + (p * 256 + wb) * 8, src + row * UNITS + kg * 8);
  }
}

// 32x32 f32->bf16 transpose tile: RT[n][k] = R[k][n]
__device__ __forceinline__ void trans_tile(const float* __restrict__ R,
                                           uint16_t* __restrict__ RT, int n0,
                                           int k0, void* smem, int tid) {
  float(*t)[33] = (float(*)[33])smem;
  const int tx = tid & 31, ty = tid >> 5;
#pragma unroll
  for (int i2 = 0; i2 < 4; ++i2)
    t[ty + i2 * 8][tx] = R[(size_t)(k0 + ty + i2 * 8) * FOURU + n0 + tx];
  __syncthreads();
#pragma unroll
  for (int i2 = 0; i2 < 4; ++i2)
    RT[(size_t)(n0 + ty + i2 * 8) * UNITS + k0 + tx] = f2bf(t[tx][ty + i2 * 8]);
}

// ---- prep: blocks [0,4096): h f32->bf16; [4096,6144): transpose z|r half ----
__global__ __launch_bounds__(256) void prep_kernel(const float* __restrict__ h32,
                                                   uint16_t* __restrict__ hbf,
                                                   const float* __restrict__ R,
                                                   uint16_t* __restrict__ RT) {
  __shared__ __align__(16) float t[32][33];
  const int b = blockIdx.x;
  if (b < 4096) {
    const int i = (b * 256 + threadIdx.x) * 4;
    float4 v = *(const float4*)(h32 + i);
    ushort4 o;
    o.x = f2bf(v.x); o.y = f2bf(v.y); o.z = f2bf(v.z); o.w = f2bf(v.w);
    *(ushort4*)(hbf + i) = o;
  } else {
    const int tt = b - 4096;  // 64 n-tiles (n<2048) x 32 k-tiles
    trans_tile(R, RT, (tt & 63) * 32, (tt >> 6) * 32, t, threadIdx.x);
  }
}

// ---- s1: blocks [0,1024): GEMM z|r (BM=64, BN=128, R4-champion schedule)
//      with kc/bias register prefetch before the K-loop;
//      blocks [1024,3072): transpose hh|o half of R (consumed by s2/s3 only
//      after this kernel's boundary -> stream-order correctness) ----
__global__ __launch_bounds__(256, 4) void s1_kernel(
    const uint16_t* __restrict__ hbf, uint16_t* rt, const int* __restrict__ idx,
    const float* __restrict__ kc, const float* __restrict__ bz,
    const float* __restrict__ bias, const float* __restrict__ R,
    uint16_t* __restrict__ zb, uint16_t* __restrict__ rhb) {
  __shared__ __align__(16) char smem[24 * 1024 + 256];
  const int tid = threadIdx.x;
  const int fid = blockIdx.x;

  if (fid >= 1024) {  // transpose duty: n in [2048,4096)
    const int tt = fid - 1024;
    trans_tile(R, rt, 2048 + (tt & 63) * 32, (tt >> 6) * 32, smem, tid);
    return;
  }

  uint16_t* sA = (uint16_t*)smem;           // [2][64*32]   8 KB
  uint16_t* sB = (uint16_t*)(smem + 8192);  // [2][128*32] 16 KB
  int* sIdx = (int*)(smem + 24 * 1024);     // 64 ints
  const int lane = tid & 63, wave = tid >> 6;
  const int l15 = lane & 15, l4 = lane >> 4;
  // T1 bijective XCD swizzle: nwg=1024, q=128
  const int nid = (fid & 7) * 128 + (fid >> 3);
  const int row0 = (nid & 63) * 64;
  const int col0 = (nid >> 6) * 128;
  const int wr = wave >> 1, wc = wave & 1;
  const uint16_t* pa = hbf + (size_t)row0 * UNITS;
  const uint16_t* pb = rt + (size_t)col0 * UNITS;
  const bool is_z = (col0 < UNITS);  // block-uniform
  f32x4 acc[2][4] = {};

  if (tid < 64) sIdx[tid] = idx[row0 + tid];
  stage32s<64>(pa, sA, tid);
  stage32s<128>(pb, sB, tid);
  __syncthreads();  // covers sIdx

  // prefetch epilogue gather (addresses depend only on sIdx); completes
  // under the K-loop's MFMA work -> removes the cold-HBM block tail.
  float kcp[2][4][4], bp[4];
#pragma unroll
  for (int n = 0; n < 4; ++n) {
    const int jc = col0 + wc * 64 + n * 16 + l15;
    bp[n] = is_z ? bz[jc] : bias[jc - UNITS];
  }
#pragma unroll
  for (int m = 0; m < 2; ++m)
#pragma unroll
    for (int q = 0; q < 4; ++q) {
      const int lr = wr * 32 + m * 16 + l4 * 4 + q;
      const float* kcrow = kc + (size_t)sIdx[lr] * FOURU;
#pragma unroll
      for (int n = 0; n < 4; ++n)
        kcp[m][q][n] = kcrow[col0 + wc * 64 + n * 16 + l15];
    }

  int cur = 0;
  for (int t = 0; t < 32; ++t) {
    if (t < 31) {  // issue next-tile loads before compute
      stage32s<64>(pa + (t + 1) * 32, sA + (cur ^ 1) * 2048, tid);
      stage32s<128>(pb + (t + 1) * 32, sB + (cur ^ 1) * 4096, tid);
    }
    const bf16x8* A8 = (const bf16x8*)(sA + cur * 2048);
    const bf16x8* B8 = (const bf16x8*)(sB + cur * 4096);
    bf16x8 af[2], bfr[4];
#pragma unroll
    for (int m = 0; m < 2; ++m) af[m] = A8[fidx(wr * 32 + m * 16 + l15, l4)];
#pragma unroll
    for (int n = 0; n < 4; ++n) bfr[n] = B8[fidx(wc * 64 + n * 16 + l15, l4)];
#pragma unroll
    for (int m = 0; m < 2; ++m)
#pragma unroll
      for (int n = 0; n < 4; ++n)
        acc[m][n] = mfma16x16x32(af[m], bfr[n], acc[m][n]);
    __syncthreads();  // drains gll_lds (vmcnt) + own ds_reads (lgkm)
    cur ^= 1;
  }

#pragma unroll
  for (int m = 0; m < 2; ++m) {
#pragma unroll
    for (int q = 0; q < 4; ++q) {
      const int lr = wr * 32 + m * 16 + l4 * 4 + q;
      const int i = row0 + lr;
#pragma unroll
      for (int n = 0; n < 4; ++n) {
        const int jc = col0 + wc * 64 + n * 16 + l15;
        const float a = acc[m][n][q] + kcp[m][q][n] + bp[n];
        if (is_z) {
          zb[(size_t)i * UNITS + jc] = f2bf(fsig(a));
        } else {
          const size_t ij = (size_t)i * UNITS + (jc - UNITS);
          // hbf row i is L2-hot from this block's own A-staging
          rhb[ij] = f2bf(fsig(a) * bf2f(hbf[ij]));
        }
      }
    }
  }
}

// ---- s2/s3: BM=64, BN=64 (R4 champion) + kc/bias register prefetch ----
// EPI 1: s2: hh=tanh(+ch+b1); hn=z*h+(1-z)*hh -> h_out(f32)+hnb(bf16)
// EPI 2: s3: o =tanh(+co+b2) -> o_out(f32)
template <int EPI>
__global__ __launch_bounds__(256, 4) void gemm_kernel(
    const uint16_t* __restrict__ abf, const uint16_t* __restrict__ bt,
    const int* __restrict__ idx, const float* __restrict__ kc,
    const float* __restrict__ bias, const uint16_t* __restrict__ hbf,
    const uint16_t* __restrict__ zb_in, float* __restrict__ out32,
    uint16_t* __restrict__ outbf) {
  __shared__ __align__(16) char smem[16 * 1024 + 256];
  uint16_t* sA = (uint16_t*)smem;           // [2][64*32] 8 KB
  uint16_t* sB = (uint16_t*)(smem + 8192);  // [2][64*32] 8 KB
  int* sIdx = (int*)(smem + 16 * 1024);     // 64 ints
  const int tid = threadIdx.x;
  const int lane = tid & 63, wave = tid >> 6;
  const int l15 = lane & 15, l4 = lane >> 4;
  // T1 bijective XCD swizzle: nwg=1024, q=128
  const int fid = blockIdx.x;
  const int nid = (fid & 7) * 128 + (fid >> 3);
  const int row0 = (nid & 63) * 64;
  const int col0 = (nid >> 6) * 64;
  const int wr = wave >> 1, wc = wave & 1;
  const uint16_t* pa = abf + (size_t)row0 * UNITS;
  const uint16_t* pb = bt + (size_t)col0 * UNITS;
  constexpr int KCOFF = (EPI == 1 ? 2 : 3) * UNITS;
  constexpr int BOFF = (EPI == 1 ? 1 : 2) * UNITS;
  f32x4 acc[2][2] = {};

  if (tid < 64) sIdx[tid] = idx[row0 + tid];
  stage32s<64>(pa, sA, tid);
  stage32s<64>(pb, sB, tid);
  __syncthreads();  // covers sIdx

  // prefetch epilogue gather (addresses depend only on sIdx)
  float kcp[2][4][2], bp[2];
#pragma unroll
  for (int n = 0; n < 2; ++n)
    bp[n] = bias[BOFF + col0 + wc * 32 + n * 16 + l15];
#pragma unroll
  for (int m = 0; m < 2; ++m)
#pragma unroll
    for (int q = 0; q < 4; ++q) {
      const int lr = wr * 32 + m * 16 + l4 * 4 + q;
      const float* kcrow = kc + (size_t)sIdx[lr] * FOURU + KCOFF;
#pragma unroll
      for (int n = 0; n < 2; ++n)
        kcp[m][q][n] = kcrow[col0 + wc * 32 + n * 16 + l15];
    }

  int cur = 0;
  for (int t = 0; t < 32; ++t) {
    if (t < 31) {
      stage32s<64>(pa + (t + 1) * 32, sA + (cur ^ 1) * 2048, tid);
      stage32s<64>(pb + (t + 1) * 32, sB + (cur ^ 1) * 2048, tid);
    }
    const bf16x8* A8 = (const bf16x8*)(sA + cur * 2048);
    const bf16x8* B8 = (const bf16x8*)(sB + cur * 2048);
    bf16x8 af[2], bfr[2];
#pragma unroll
    for (int m = 0; m < 2; ++m) af[m] = A8[fidx(wr * 32 + m * 16 + l15, l4)];
#pragma unroll
    for (int n = 0; n < 2; ++n) bfr[n] = B8[fidx(wc * 32 + n * 16 + l15, l4)];
#pragma unroll
    for (int m = 0; m < 2; ++m)
#pragma unroll
      for (int n = 0; n < 2; ++n)
        acc[m][n] = mfma16x16x32(af[m], bfr[n], acc[m][n]);
    __syncthreads();
    cur ^= 1;
  }

#pragma unroll
  for (int m = 0; m < 2; ++m) {
#pragma unroll
    for (int q = 0; q < 4; ++q) {
      const int i = row0 + wr * 32 + m * 16 + l4 * 4 + q;
#pragma unroll
      for (int n = 0; n < 2; ++n) {
        const int jc = col0 + wc * 32 + n * 16 + l15;
        const size_t ij = (size_t)i * UNITS + jc;
        const float a = acc[m][n][q] + kcp[m][q][n] + bp[n];
        if (EPI == 1) {
          float hh = tanhf(a);
          float z = bf2f(zb_in[ij]);
          float hv = bf2f(hbf[ij]);
          float hn = z * hv + (1.0f - z) * hh;
          out32[ij] = hn;
          outbf[ij] = f2bf(hn);
        } else {
          out32[ij] = tanhf(a);
        }
      }
    }
  }
}

extern "C" void kernel_launch(void* const* d_in, const int* in_sizes, int n_in,
                              void* d_out, int out_size, void* d_ws, size_t ws_size,
                              hipStream_t stream) {
  const int* idx = (const int*)d_in[0];
  const float* h32 = (const float*)d_in[1];
  const float* R = (const float*)d_in[2];
  const float* kc = (const float*)d_in[3];
  const float* bz = (const float*)d_in[4];
  const float* bias = (const float*)d_in[5];

  float* o_out = (float*)d_out;                  // 4M f32 (output o)
  float* h_out = o_out + (size_t)BATCH * UNITS;  // 4M f32 (output h)

  uint16_t* hbf = (uint16_t*)d_ws;               // bf16(h_tm1)   8 MB
  uint16_t* rt = hbf + (size_t)BATCH * UNITS;    // bf16(R^T)     8 MB
  uint16_t* rhb = rt + (size_t)FOURU * UNITS;    // bf16(r*h)     8 MB
  uint16_t* hnb = rhb + (size_t)BATCH * UNITS;   // bf16(h_new)   8 MB
  uint16_t* zbuf = hnb + (size_t)BATCH * UNITS;  // bf16(z)       8 MB

  // prep: h convert (4096 blocks) + z|r transpose half (2048 blocks)
  prep_kernel<<<dim3(6144), 256, 0, stream>>>(h32, hbf, R, rt);

  // s1: 1024 GEMM blocks + 2048 transpose blocks (hh|o half of R)
  s1_kernel<<<dim3(3072), 256, 0, stream>>>(hbf, rt, idx, kc, bz, bias, R,
                                            zbuf, rhb);

  // s2: N=1024 -> 1024 blocks
  gemm_kernel<1><<<dim3(1024), 256, 0, stream>>>(
      rhb, rt + (size_t)2 * UNITS * UNITS, idx, kc, bias, hbf, zbuf, h_out,
      hnb);

  // s3: N=1024 -> 1024 blocks
  gemm_kernel<2><<<dim3(1024), 256, 0, stream>>>(
      hnb, rt + (size_t)3 * UNITS * UNITS, idx, kc, bias, nullptr, nullptr,
      o_out, nullptr);
}

// Round 12
// 102.528 us; speedup vs baseline: 1.0168x; 1.0168x over previous
//
#include <hip/hip_runtime.h>
#include <stdint.h>

#define UNITS 1024
#define BATCH 4096
#define FOURU 4096

typedef __bf16 bf16x8 __attribute__((ext_vector_type(8)));
typedef float f32x4 __attribute__((ext_vector_type(4)));

// round-to-nearest-even f32 -> bf16
__device__ __forceinline__ uint16_t f2bf(float f) {
  uint32_t u = __builtin_bit_cast(uint32_t, f);
  u += 0x7FFFu + ((u >> 16) & 1u);
  return (uint16_t)(u >> 16);
}
__device__ __forceinline__ float bf2f(uint16_t b) {
  uint32_t u = ((uint32_t)b) << 16;
  return __builtin_bit_cast(float, u);
}
__device__ __forceinline__ float fsig(float x) {
  return 1.0f / (1.0f + __expf(-x));
}
__device__ __forceinline__ f32x4 mfma16x16x32(bf16x8 a, bf16x8 b, f32x4 c) {
  return __builtin_amdgcn_mfma_f32_16x16x32_bf16(a, b, c, 0, 0, 0);
}

// async global->LDS, 16B per lane; LDS dest wave-uniform base (+lane*16 HW)
__device__ __forceinline__ void gll16(uint16_t* lds, const uint16_t* g) {
  __builtin_amdgcn_global_load_lds(
      (const __attribute__((address_space(1))) uint32_t*)g,
      (__attribute__((address_space(3))) uint32_t*)lds, 16, 0, 0);
}

// Granule swizzle (BK=32 tile = [ROWS][4 granules of 8 bf16]); stored granule
// (row,s) holds global (row, kg = s ^ ((row>>1)&3)). gload_lds dest LINEAR;
// permutation in per-lane GLOBAL source. Verified: conflicts 2.1M -> 0.
__device__ __forceinline__ int fidx(int row, int l4) {
  return row * 4 + (l4 ^ ((row >> 1) & 3));
}

template <int ROWS>
__device__ __forceinline__ void stage32s(const uint16_t* __restrict__ src,
                                         uint16_t* lds, int tid) {
  const int wb = tid & 192;  // wave*64 granules (linear LDS dest)
#pragma unroll
  for (int p = 0; p < ROWS / 64; ++p) {
    const int gi = p * 256 + tid;
    const int row = gi >> 2;
    const int kg = (gi & 3) ^ ((row >> 1) & 3);
    gll16(lds + (p * 256 + wb) * 8, src + row * UNITS + kg * 8);
  }
}

// BK=64 tile as TWO k-half sub-tiles, each [64][32] with the granule swizzle
// (R3-verified layout). Half h occupies granules [h*256, h*256+256).
__device__ __forceinline__ void stage64h(const uint16_t* __restrict__ src,
                                         uint16_t* lds, int tid) {
  const int wb = tid & 192;
#pragma unroll
  for (int p = 0; p < 2; ++p) {
    const int gi = p * 256 + tid;
    const int h = gi >> 8;               // k-half
    const int r = (gi >> 2) & 63;        // row within half
    const int kg = (gi & 3) ^ ((r >> 1) & 3);
    gll16(lds + (p * 256 + wb) * 8, src + r * UNITS + h * 32 + kg * 8);
  }
}

// 32x32 f32->bf16 transpose tile: RT[n][k] = R[k][n]
__device__ __forceinline__ void trans_tile(const float* __restrict__ R,
                                           uint16_t* __restrict__ RT, int n0,
                                           int k0, void* smem, int tid) {
  float(*t)[33] = (float(*)[33])smem;
  const int tx = tid & 31, ty = tid >> 5;
#pragma unroll
  for (int i2 = 0; i2 < 4; ++i2)
    t[ty + i2 * 8][tx] = R[(size_t)(k0 + ty + i2 * 8) * FOURU + n0 + tx];
  __syncthreads();
#pragma unroll
  for (int i2 = 0; i2 < 4; ++i2)
    RT[(size_t)(n0 + ty + i2 * 8) * UNITS + k0 + tx] = f2bf(t[tx][ty + i2 * 8]);
}

// ---- prep: blocks [0,4096): h f32->bf16; [4096,6144): transpose z|r half ----
__global__ __launch_bounds__(256) void prep_kernel(const float* __restrict__ h32,
                                                   uint16_t* __restrict__ hbf,
                                                   const float* __restrict__ R,
                                                   uint16_t* __restrict__ RT) {
  __shared__ __align__(16) float t[32][33];
  const int b = blockIdx.x;
  if (b < 4096) {
    const int i = (b * 256 + threadIdx.x) * 4;
    float4 v = *(const float4*)(h32 + i);
    ushort4 o;
    o.x = f2bf(v.x); o.y = f2bf(v.y); o.z = f2bf(v.z); o.w = f2bf(v.w);
    *(ushort4*)(hbf + i) = o;
  } else {
    const int tt = b - 4096;  // 64 n-tiles (n<2048) x 32 k-tiles
    trans_tile(R, RT, (tt & 63) * 32, (tt >> 6) * 32, t, threadIdx.x);
  }
}

// ---- s1: blocks [0,1024): GEMM z|r (BM=64, BN=128, champion schedule)
//      + kc/bias register prefetch; blocks [1024,3072): transpose hh|o half ----
__global__ __launch_bounds__(256, 4) void s1_kernel(
    const uint16_t* __restrict__ hbf, uint16_t* rt, const int* __restrict__ idx,
    const float* __restrict__ kc, const float* __restrict__ bz,
    const float* __restrict__ bias, const float* __restrict__ R,
    uint16_t* __restrict__ zb, uint16_t* __restrict__ rhb) {
  __shared__ __align__(16) char smem[24 * 1024 + 256];
  const int tid = threadIdx.x;
  const int fid = blockIdx.x;

  if (fid >= 1024) {  // transpose duty: n in [2048,4096)
    const int tt = fid - 1024;
    trans_tile(R, rt, 2048 + (tt & 63) * 32, (tt >> 6) * 32, smem, tid);
    return;
  }

  uint16_t* sA = (uint16_t*)smem;           // [2][64*32]   8 KB
  uint16_t* sB = (uint16_t*)(smem + 8192);  // [2][128*32] 16 KB
  int* sIdx = (int*)(smem + 24 * 1024);     // 64 ints
  const int lane = tid & 63, wave = tid >> 6;
  const int l15 = lane & 15, l4 = lane >> 4;
  const int nid = (fid & 7) * 128 + (fid >> 3);  // T1 bijective XCD swizzle
  const int row0 = (nid & 63) * 64;
  const int col0 = (nid >> 6) * 128;
  const int wr = wave >> 1, wc = wave & 1;
  const uint16_t* pa = hbf + (size_t)row0 * UNITS;
  const uint16_t* pb = rt + (size_t)col0 * UNITS;
  const bool is_z = (col0 < UNITS);  // block-uniform
  f32x4 acc[2][4] = {};

  if (tid < 64) sIdx[tid] = idx[row0 + tid];
  stage32s<64>(pa, sA, tid);
  stage32s<128>(pb, sB, tid);
  __syncthreads();  // covers sIdx

  // prefetch epilogue gather (addresses depend only on sIdx)
  float kcp[2][4][4], bp[4];
#pragma unroll
  for (int n = 0; n < 4; ++n) {
    const int jc = col0 + wc * 64 + n * 16 + l15;
    bp[n] = is_z ? bz[jc] : bias[jc - UNITS];
  }
#pragma unroll
  for (int m = 0; m < 2; ++m)
#pragma unroll
    for (int q = 0; q < 4; ++q) {
      const int lr = wr * 32 + m * 16 + l4 * 4 + q;
      const float* kcrow = kc + (size_t)sIdx[lr] * FOURU;
#pragma unroll
      for (int n = 0; n < 4; ++n)
        kcp[m][q][n] = kcrow[col0 + wc * 64 + n * 16 + l15];
    }

  int cur = 0;
  for (int t = 0; t < 32; ++t) {
    if (t < 31) {  // issue next-tile loads before compute
      stage32s<64>(pa + (t + 1) * 32, sA + (cur ^ 1) * 2048, tid);
      stage32s<128>(pb + (t + 1) * 32, sB + (cur ^ 1) * 4096, tid);
    }
    const bf16x8* A8 = (const bf16x8*)(sA + cur * 2048);
    const bf16x8* B8 = (const bf16x8*)(sB + cur * 4096);
    bf16x8 af[2], bfr[4];
#pragma unroll
    for (int m = 0; m < 2; ++m) af[m] = A8[fidx(wr * 32 + m * 16 + l15, l4)];
#pragma unroll
    for (int n = 0; n < 4; ++n) bfr[n] = B8[fidx(wc * 64 + n * 16 + l15, l4)];
#pragma unroll
    for (int m = 0; m < 2; ++m)
#pragma unroll
      for (int n = 0; n < 4; ++n)
        acc[m][n] = mfma16x16x32(af[m], bfr[n], acc[m][n]);
    __syncthreads();  // drains gll_lds (vmcnt) + own ds_reads (lgkm)
    cur ^= 1;
  }

#pragma unroll
  for (int m = 0; m < 2; ++m) {
#pragma unroll
    for (int q = 0; q < 4; ++q) {
      const int lr = wr * 32 + m * 16 + l4 * 4 + q;
      const int i = row0 + lr;
#pragma unroll
      for (int n = 0; n < 4; ++n) {
        const int jc = col0 + wc * 64 + n * 16 + l15;
        const float a = acc[m][n][q] + kcp[m][q][n] + bp[n];
        if (is_z) {
          zb[(size_t)i * UNITS + jc] = f2bf(fsig(a));
        } else {
          const size_t ij = (size_t)i * UNITS + (jc - UNITS);
          rhb[ij] = f2bf(fsig(a) * bf2f(hbf[ij]));
        }
      }
    }
  }
}

// ---- s2/s3: BM=64, BN=64, **BK=64** (half-split LDS), 16 barrier steps ----
// EPI 1: s2: hh=tanh(+ch+b1); hn=z*h+(1-z)*hh -> h_out(f32)+hnb(bf16)
// EPI 2: s3: o =tanh(+co+b2) -> o_out(f32)
template <int EPI>
__global__ __launch_bounds__(256, 4) void gemm_kernel(
    const uint16_t* __restrict__ abf, const uint16_t* __restrict__ bt,
    const int* __restrict__ idx, const float* __restrict__ kc,
    const float* __restrict__ bias, const uint16_t* __restrict__ hbf,
    const uint16_t* __restrict__ zb_in, float* __restrict__ out32,
    uint16_t* __restrict__ outbf) {
  __shared__ __align__(16) char smem[32 * 1024 + 256];
  uint16_t* sA = (uint16_t*)smem;            // [2][64*64] 16 KB
  uint16_t* sB = (uint16_t*)(smem + 16384);  // [2][64*64] 16 KB
  int* sIdx = (int*)(smem + 32 * 1024);      // 64 ints
  const int tid = threadIdx.x;
  const int lane = tid & 63, wave = tid >> 6;
  const int l15 = lane & 15, l4 = lane >> 4;
  const int fid = blockIdx.x;
  const int nid = (fid & 7) * 128 + (fid >> 3);  // T1 bijective XCD swizzle
  const int row0 = (nid & 63) * 64;
  const int col0 = (nid >> 6) * 64;
  const int wr = wave >> 1, wc = wave & 1;
  const uint16_t* pa = abf + (size_t)row0 * UNITS;
  const uint16_t* pb = bt + (size_t)col0 * UNITS;
  constexpr int KCOFF = (EPI == 1 ? 2 : 3) * UNITS;
  constexpr int BOFF = (EPI == 1 ? 1 : 2) * UNITS;
  f32x4 acc[2][2] = {};

  if (tid < 64) sIdx[tid] = idx[row0 + tid];
  stage64h(pa, sA, tid);
  stage64h(pb, sB, tid);
  __syncthreads();  // covers sIdx

  // prefetch epilogue gather (addresses depend only on sIdx)
  float kcp[2][4][2], bp[2];
#pragma unroll
  for (int n = 0; n < 2; ++n)
    bp[n] = bias[BOFF + col0 + wc * 32 + n * 16 + l15];
#pragma unroll
  for (int m = 0; m < 2; ++m)
#pragma unroll
    for (int q = 0; q < 4; ++q) {
      const int lr = wr * 32 + m * 16 + l4 * 4 + q;
      const float* kcrow = kc + (size_t)sIdx[lr] * FOURU + KCOFF;
#pragma unroll
      for (int n = 0; n < 2; ++n)
        kcp[m][q][n] = kcrow[col0 + wc * 32 + n * 16 + l15];
    }

  int cur = 0;
  for (int t = 0; t < 16; ++t) {  // BK=64: 16 barrier steps (vs 32)
    if (t < 15) {
      stage64h(pa + (t + 1) * 64, sA + (cur ^ 1) * 4096, tid);
      stage64h(pb + (t + 1) * 64, sB + (cur ^ 1) * 4096, tid);
    }
    const bf16x8* A8 = (const bf16x8*)(sA + cur * 4096);
    const bf16x8* B8 = (const bf16x8*)(sB + cur * 4096);
#pragma unroll
    for (int h = 0; h < 2; ++h) {
      bf16x8 af[2], bfr[2];
#pragma unroll
      for (int m = 0; m < 2; ++m)
        af[m] = A8[h * 256 + fidx(wr * 32 + m * 16 + l15, l4)];
#pragma unroll
      for (int n = 0; n < 2; ++n)
        bfr[n] = B8[h * 256 + fidx(wc * 32 + n * 16 + l15, l4)];
#pragma unroll
      for (int m = 0; m < 2; ++m)
#pragma unroll
        for (int n = 0; n < 2; ++n)
          acc[m][n] = mfma16x16x32(af[m], bfr[n], acc[m][n]);
    }
    __syncthreads();
    cur ^= 1;
  }

#pragma unroll
  for (int m = 0; m < 2; ++m) {
#pragma unroll
    for (int q = 0; q < 4; ++q) {
      const int i = row0 + wr * 32 + m * 16 + l4 * 4 + q;
#pragma unroll
      for (int n = 0; n < 2; ++n) {
        const int jc = col0 + wc * 32 + n * 16 + l15;
        const size_t ij = (size_t)i * UNITS + jc;
        const float a = acc[m][n][q] + kcp[m][q][n] + bp[n];
        if (EPI == 1) {
          float hh = tanhf(a);
          float z = bf2f(zb_in[ij]);
          float hv = bf2f(hbf[ij]);
          float hn = z * hv + (1.0f - z) * hh;
          out32[ij] = hn;
          outbf[ij] = f2bf(hn);
        } else {
          out32[ij] = tanhf(a);
        }
      }
    }
  }
}

extern "C" void kernel_launch(void* const* d_in, const int* in_sizes, int n_in,
                              void* d_out, int out_size, void* d_ws, size_t ws_size,
                              hipStream_t stream) {
  const int* idx = (const int*)d_in[0];
  const float* h32 = (const float*)d_in[1];
  const float* R = (const float*)d_in[2];
  const float* kc = (const float*)d_in[3];
  const float* bz = (const float*)d_in[4];
  const float* bias = (const float*)d_in[5];

  float* o_out = (float*)d_out;                  // 4M f32 (output o)
  float* h_out = o_out + (size_t)BATCH * UNITS;  // 4M f32 (output h)

  uint16_t* hbf = (uint16_t*)d_ws;               // bf16(h_tm1)   8 MB
  uint16_t* rt = hbf + (size_t)BATCH * UNITS;    // bf16(R^T)     8 MB
  uint16_t* rhb = rt + (size_t)FOURU * UNITS;    // bf16(r*h)     8 MB
  uint16_t* hnb = rhb + (size_t)BATCH * UNITS;   // bf16(h_new)   8 MB
  uint16_t* zbuf = hnb + (size_t)BATCH * UNITS;  // bf16(z)       8 MB

  // prep: h convert (4096 blocks) + z|r transpose half (2048 blocks)
  prep_kernel<<<dim3(6144), 256, 0, stream>>>(h32, hbf, R, rt);

  // s1: 1024 GEMM blocks + 2048 transpose blocks (hh|o half of R)
  s1_kernel<<<dim3(3072), 256, 0, stream>>>(hbf, rt, idx, kc, bz, bias, R,
                                            zbuf, rhb);

  // s2: N=1024 -> 1024 blocks
  gemm_kernel<1><<<dim3(1024), 256, 0, stream>>>(
      rhb, rt + (size_t)2 * UNITS * UNITS, idx, kc, bias, hbf, zbuf, h_out,
      hnb);

  // s3: N=1024 -> 1024 blocks
  gemm_kernel<2><<<dim3(1024), 256, 0, stream>>>(
      hnb, rt + (size_t)3 * UNITS * UNITS, idx, kc, bias, nullptr, nullptr,
      o_out, nullptr);
}